// Round 2
// baseline (1522.915 us; speedup 1.0000x reference)
//
#include <hip/hip_runtime.h>

typedef unsigned short u16;
typedef unsigned int u32;
typedef unsigned long long u64;
typedef __bf16 bf16x8 __attribute__((ext_vector_type(8)));
typedef float f32x4 __attribute__((ext_vector_type(4)));

#define AS1 __attribute__((address_space(1)))
#define AS3 __attribute__((address_space(3)))

__device__ __forceinline__ float bf2f(u32 v) {
    u32 u = v << 16;
    float f;
    __builtin_memcpy(&f, &u, 4);
    return f;
}
__device__ __forceinline__ u16 f2bf(float f) {
    u32 u;
    __builtin_memcpy(&u, &f, 4);
    u32 r = u + 0x7FFFu + ((u >> 16) & 1u);
    return (u16)(r >> 16);
}

// ---------------------------------------------------------------------------
// GEMM: C = A @ Bt^T (+bias) [SCORES: fp32 C = acc*scale + mask] [RELU]
// A: [M x K] row-major (lda) - bf16, or fp32 when AF32 (converted in-register)
// Bt: [N x K] row-major (ldb) - bf16
// batching: z -> b = z/batchH, h = z%batchH ; base += b*Xob + h*Xoh
// m97 structure: BK=32, global_load_lds width 16, 16x16x32 bf16 MFMA,
// XOR-swizzled LDS chunks (<=2-way bank aliasing = free).
// ---------------------------------------------------------------------------
template <int BM, int BN, bool RELU, bool SCORES, bool AF32>
__global__ __launch_bounds__(256) void gemm_bt(
    const void* __restrict__ Av, const u16* __restrict__ Bt,
    const float* __restrict__ bias, void* __restrict__ Cv,
    int lda, int ldb, int ldc, int K,
    long Aob, long Aoh, long Bob, long Boh, long Cob, long Coh,
    int batchH, const float* __restrict__ mask, float scale)
{
    const int tid = threadIdx.x;
    const int z = blockIdx.z;
    const int bb = z / batchH, hh = z % batchH;
    const u16*   A16 = AF32 ? nullptr : ((const u16*)Av + (size_t)bb * Aob + (size_t)hh * Aoh);
    const float* A32 = AF32 ? ((const float*)Av + (size_t)bb * Aob + (size_t)hh * Aoh) : nullptr;
    Bt += (size_t)bb * Bob + (size_t)hh * Boh;
    u16*   C16 = SCORES ? nullptr : ((u16*)Cv + (size_t)bb * Cob + (size_t)hh * Coh);
    float* C32 = SCORES ? ((float*)Cv + (size_t)bb * Cob + (size_t)hh * Coh) : nullptr;
    const float* maskp = SCORES ? (mask + ((size_t)bb << 20)) : nullptr;

    const int m0 = blockIdx.y * BM;
    const int n0 = blockIdx.x * BN;

    __shared__ bf16x8 As[AF32 ? BM * 8 : BM * 4];   // 16B slots
    __shared__ bf16x8 Bs[BN * 4];

    constexpr int TM = (BN == 128) ? 4 : 2;
    constexpr int TN = 4;
    const int wave = tid >> 6, lane = tid & 63;
    const int wr = (BN == 128) ? (wave >> 1) : wave;
    const int wc = (BN == 128) ? (wave & 1) : 0;
    const int row_base = wr * (TM * 16);
    const int col_base = wc * 64;
    const int quad = lane >> 4, l16 = lane & 15;

    f32x4 acc[TM][TN] = {};

    for (int k0 = 0; k0 < K; k0 += 32) {
        if (AF32) {
            // A tile [BM x 32] fp32: slot s holds (row=s>>3, chunk4 gq=(s&7)^(row&7))
#pragma unroll
            for (int i = 0; i < (BM * 8) / 256; ++i) {
                int s = tid + i * 256;
                int row = s >> 3;
                int gq = (s & 7) ^ (row & 7);
                const float* gp = A32 + (size_t)(m0 + row) * lda + k0 + gq * 4;
                __builtin_amdgcn_global_load_lds((AS1 const void*)gp, (AS3 void*)&As[s], 16, 0, 0);
            }
        } else {
            // A tile [BM x 32] bf16: slot s holds (row=s>>2, chunk8 gq=(s&3)^((s>>3)&3))
#pragma unroll
            for (int i = 0; i < (BM * 4) / 256; ++i) {
                int s = tid + i * 256;
                int row = s >> 2;
                int gq = (s & 3) ^ ((s >> 3) & 3);
                const u16* gp = A16 + (size_t)(m0 + row) * lda + k0 + gq * 8;
                __builtin_amdgcn_global_load_lds((AS1 const void*)gp, (AS3 void*)&As[s], 16, 0, 0);
            }
        }
#pragma unroll
        for (int i = 0; i < (BN * 4) / 256; ++i) {
            int s = tid + i * 256;
            int row = s >> 2;
            int gq = (s & 3) ^ ((s >> 3) & 3);
            const u16* gp = Bt + (size_t)(n0 + row) * ldb + k0 + gq * 8;
            __builtin_amdgcn_global_load_lds((AS1 const void*)gp, (AS3 void*)&Bs[s], 16, 0, 0);
        }
        __syncthreads();

        bf16x8 af[TM], bfr[TN];
#pragma unroll
        for (int ri = 0; ri < TM; ++ri) {
            int r = row_base + ri * 16 + l16;
            if (AF32) {
                const f32x4* Asf = (const f32x4*)As;
                int rx = r & 7;
                f32x4 a0 = Asf[r * 8 + ((2 * quad) ^ rx)];
                f32x4 a1 = Asf[r * 8 + ((2 * quad + 1) ^ rx)];
                union { bf16x8 v; u16 u[8]; } cc;
                cc.u[0] = f2bf(a0[0]); cc.u[1] = f2bf(a0[1]);
                cc.u[2] = f2bf(a0[2]); cc.u[3] = f2bf(a0[3]);
                cc.u[4] = f2bf(a1[0]); cc.u[5] = f2bf(a1[1]);
                cc.u[6] = f2bf(a1[2]); cc.u[7] = f2bf(a1[3]);
                af[ri] = cc.v;
            } else {
                af[ri] = As[r * 4 + (quad ^ ((r >> 1) & 3))];
            }
        }
#pragma unroll
        for (int cj = 0; cj < TN; ++cj) {
            int c = col_base + cj * 16 + l16;
            bfr[cj] = Bs[c * 4 + (quad ^ ((c >> 1) & 3))];
        }
#pragma unroll
        for (int ri = 0; ri < TM; ++ri)
#pragma unroll
            for (int cj = 0; cj < TN; ++cj)
                acc[ri][cj] = __builtin_amdgcn_mfma_f32_16x16x32_bf16(af[ri], bfr[cj], acc[ri][cj], 0, 0, 0);
        __syncthreads();
    }

    // epilogue: C/D layout col = lane&15, row = quad*4 + reg
#pragma unroll
    for (int ri = 0; ri < TM; ++ri) {
#pragma unroll
        for (int cj = 0; cj < TN; ++cj) {
            const int col = n0 + col_base + cj * 16 + l16;
            const float bv = (!SCORES && bias) ? bias[col] : 0.0f;
#pragma unroll
            for (int r = 0; r < 4; ++r) {
                const int row = m0 + row_base + ri * 16 + quad * 4 + r;
                float v = acc[ri][cj][r];
                if (SCORES) {
                    C32[(size_t)row * ldc + col] = v * scale + maskp[((size_t)row << 10) + col];
                } else {
                    v += bv;
                    if (RELU) v = fmaxf(v, 0.0f);
                    C16[(size_t)row * ldc + col] = f2bf(v);
                }
            }
        }
    }
}

// ---------------------------------------------------------------------------
// fp32 -> bf16 transpose: dst[c][r] = cvt(src[r][c]); grid (C/32, R/32), block (32,8)
// ---------------------------------------------------------------------------
__global__ void transpose_cvt(const float* __restrict__ src, u16* __restrict__ dst, int R, int C)
{
    __shared__ u16 t[32][33];
    const int c0 = blockIdx.x << 5, r0 = blockIdx.y << 5;
    const int tx = threadIdx.x, ty = threadIdx.y;
#pragma unroll
    for (int i = 0; i < 4; ++i) {
        int r = r0 + ty * 4 + i;
        t[ty * 4 + i][tx] = f2bf(src[(size_t)r * C + c0 + tx]);
    }
    __syncthreads();
#pragma unroll
    for (int i = 0; i < 4; ++i) {
        int c = c0 + ty * 4 + i;
        dst[(size_t)c * R + r0 + tx] = t[tx][ty * 4 + i];
    }
}

// fp32 -> bf16 straight copy, 4 elems/thread; grid = n/1024
__global__ __launch_bounds__(256) void cvt4(const float* __restrict__ src, u16* __restrict__ dst)
{
    size_t i = (size_t)blockIdx.x * 256 + threadIdx.x;
    f32x4 v = ((const f32x4*)src)[i];
    u64 o = (u64)f2bf(v[0]) | ((u64)f2bf(v[1]) << 16) | ((u64)f2bf(v[2]) << 32) | ((u64)f2bf(v[3]) << 48);
    ((u64*)dst)[i] = o;
}

// V (B,S,D) bf16 -> VT [(b*16+h)][64][1024] ; grid (32, 2, 64), block (32,8)
__global__ void transpose_v(const u16* __restrict__ v, u16* __restrict__ vt)
{
    __shared__ u16 t[32][33];
    const int z = blockIdx.z, b = z >> 4, h = z & 15;
    const int s0 = blockIdx.x << 5, d0 = blockIdx.y << 5;
    const int tx = threadIdx.x, ty = threadIdx.y;
    const u16* src = v + ((size_t)b << 20) + h * 64;
#pragma unroll
    for (int i = 0; i < 4; ++i) {
        int s = s0 + ty * 4 + i;
        t[ty * 4 + i][tx] = src[((size_t)s << 10) + d0 + tx];
    }
    __syncthreads();
    u16* dst = vt + ((size_t)z << 16);
#pragma unroll
    for (int i = 0; i < 4; ++i) {
        int d = d0 + ty * 4 + i;
        dst[((size_t)d << 10) + s0 + tx] = t[tx][ty * 4 + i];
    }
}

// ---------------------------------------------------------------------------
// in-place fp32 row softmax over 1024 cols; one block per row
// ---------------------------------------------------------------------------
__global__ __launch_bounds__(256) void softmax_rows_f32(float* __restrict__ data)
{
    float* p = data + ((size_t)blockIdx.x << 10);
    const int t = threadIdx.x;
    f32x4 v = ((const f32x4*)p)[t];
    float mx = fmaxf(fmaxf(v[0], v[1]), fmaxf(v[2], v[3]));
#pragma unroll
    for (int off = 32; off > 0; off >>= 1) mx = fmaxf(mx, __shfl_xor(mx, off));
    __shared__ float sred[4];
    const int wave = t >> 6, lane = t & 63;
    if (lane == 0) sred[wave] = mx;
    __syncthreads();
    mx = fmaxf(fmaxf(sred[0], sred[1]), fmaxf(sred[2], sred[3]));
    __syncthreads();
    float e0 = __expf(v[0] - mx), e1 = __expf(v[1] - mx);
    float e2 = __expf(v[2] - mx), e3 = __expf(v[3] - mx);
    float s = e0 + e1 + e2 + e3;
#pragma unroll
    for (int off = 32; off > 0; off >>= 1) s += __shfl_xor(s, off);
    if (lane == 0) sred[wave] = s;
    __syncthreads();
    const float inv = 1.0f / (sred[0] + sred[1] + sred[2] + sred[3]);
    f32x4 o;
    o[0] = e0 * inv; o[1] = e1 * inv; o[2] = e2 * inv; o[3] = e3 * inv;
    ((f32x4*)p)[t] = o;
}

// ---------------------------------------------------------------------------
// out = LayerNorm(a + b) * g + be ; a bf16, b fp32 (B_F32) or bf16
// writes bf16 out (if non-null) and fp32 outf (if non-null)
// ---------------------------------------------------------------------------
template <bool B_F32>
__global__ __launch_bounds__(256) void add_ln(
    const u16* __restrict__ a, const void* __restrict__ bvp,
    const float* __restrict__ g, const float* __restrict__ be,
    u16* __restrict__ out, float* __restrict__ outf)
{
    const size_t row = blockIdx.x;
    const int t = threadIdx.x;
    uint2 va = ((const uint2*)(a + (row << 10)))[t];
    float f0 = bf2f(va.x & 0xffffu), f1 = bf2f(va.x >> 16);
    float f2 = bf2f(va.y & 0xffffu), f3 = bf2f(va.y >> 16);
    if (B_F32) {
        f32x4 vb = ((const f32x4*)((const float*)bvp + (row << 10)))[t];
        f0 += vb[0]; f1 += vb[1]; f2 += vb[2]; f3 += vb[3];
    } else {
        uint2 vb = ((const uint2*)((const u16*)bvp + (row << 10)))[t];
        f0 += bf2f(vb.x & 0xffffu); f1 += bf2f(vb.x >> 16);
        f2 += bf2f(vb.y & 0xffffu); f3 += bf2f(vb.y >> 16);
    }
    float s = f0 + f1 + f2 + f3;
    float q = f0 * f0 + f1 * f1 + f2 * f2 + f3 * f3;
#pragma unroll
    for (int off = 32; off > 0; off >>= 1) {
        s += __shfl_xor(s, off);
        q += __shfl_xor(q, off);
    }
    __shared__ float rs[4], rq[4];
    const int wave = t >> 6, lane = t & 63;
    if (lane == 0) { rs[wave] = s; rq[wave] = q; }
    __syncthreads();
    s = rs[0] + rs[1] + rs[2] + rs[3];
    q = rq[0] + rq[1] + rq[2] + rq[3];
    const float mean = s * (1.0f / 1024.0f);
    const float var = q * (1.0f / 1024.0f) - mean * mean;
    const float rstd = rsqrtf(var + 1e-5f);
    f32x4 vg = ((const f32x4*)g)[t];
    f32x4 ve = ((const f32x4*)be)[t];
    float r0 = (f0 - mean) * rstd * vg[0] + ve[0];
    float r1 = (f1 - mean) * rstd * vg[1] + ve[1];
    float r2 = (f2 - mean) * rstd * vg[2] + ve[2];
    float r3 = (f3 - mean) * rstd * vg[3] + ve[3];
    if (out) {
        u32 o0 = (u32)f2bf(r0) | ((u32)f2bf(r1) << 16);
        u32 o1 = (u32)f2bf(r2) | ((u32)f2bf(r3) << 16);
        ((uint2*)(out + (row << 10)))[t] = make_uint2(o0, o1);
    }
    if (outf) {
        f32x4 o; o[0] = r0; o[1] = r1; o[2] = r2; o[3] = r3;
        ((f32x4*)(outf + (row << 10)))[t] = o;
    }
}

// ---------------------------------------------------------------------------
extern "C" void kernel_launch(void* const* d_in, const int* in_sizes, int n_in,
                              void* d_out, int out_size, void* d_ws, size_t ws_size,
                              hipStream_t stream)
{
    const float* X    = (const float*)d_in[0];
    const float* ENC  = (const float*)d_in[1];
    const float* MPAD = (const float*)d_in[2];   // cross-attn mask (B,1,S,S)
    const float* MSUB = (const float*)d_in[3];   // self-attn mask
    const float* Wq1 = (const float*)d_in[4],  *bq1 = (const float*)d_in[5];
    const float* Wk1 = (const float*)d_in[6],  *bk1 = (const float*)d_in[7];
    const float* Wv1 = (const float*)d_in[8],  *bv1 = (const float*)d_in[9];
    const float* Wo1 = (const float*)d_in[10], *bo1 = (const float*)d_in[11];
    const float* Wq2 = (const float*)d_in[12], *bq2 = (const float*)d_in[13];
    const float* Wk2 = (const float*)d_in[14], *bk2 = (const float*)d_in[15];
    const float* Wv2 = (const float*)d_in[16], *bv2 = (const float*)d_in[17];
    const float* Wo2 = (const float*)d_in[18], *bo2 = (const float*)d_in[19];
    const float* Wf1 = (const float*)d_in[20], *bf1 = (const float*)d_in[21];
    const float* Wf2 = (const float*)d_in[22], *bf2v = (const float*)d_in[23];
    const float* g1 = (const float*)d_in[24], *be1 = (const float*)d_in[25];
    const float* g2 = (const float*)d_in[26], *be2 = (const float*)d_in[27];
    const float* g3 = (const float*)d_in[28], *be3 = (const float*)d_in[29];

    float* OUT3 = (float*)d_out;
    float* AW1  = OUT3 + 4194304;      // (B,H,S,S) fp32
    float* AW2  = AW1 + 67108864;

    u16* ws = (u16*)d_ws;
    const size_t M1 = 1048576;
    u16* WTq1 = ws + 0 * M1, *WTk1 = ws + 1 * M1, *WTv1 = ws + 2 * M1, *WTo1 = ws + 3 * M1;
    u16* WTq2 = ws + 4 * M1, *WTk2 = ws + 5 * M1, *WTv2 = ws + 6 * M1, *WTo2 = ws + 7 * M1;
    u16* WTF1 = ws + 8 * M1;    // [4096][1024]
    u16* WTF2 = ws + 12 * M1;   // [1024][4096]
    u16* Xbf  = ws + 16 * M1;   // (B,S,D) bf16
    u16* ENCb = ws + 20 * M1;
    u16* Qb = ws + 24 * M1, *Kb = ws + 28 * M1, *Vb = ws + 32 * M1, *VT = ws + 36 * M1;
    u16* Hb = Qb;               // FFN hidden [4096][4096] bf16 reuses Qb..VT (dead then)
    u16* ATT = ws + 40 * M1, *TMP = ws + 44 * M1, *O1 = ws + 48 * M1, *O2 = ws + 52 * M1;

    const dim3 tb(32, 8);
    // --- input/weight conversion (inputs restored before every launch) ---
    cvt4<<<4096, 256, 0, stream>>>(X, Xbf);
    cvt4<<<4096, 256, 0, stream>>>(ENC, ENCb);
    transpose_cvt<<<dim3(32, 32), tb, 0, stream>>>(Wq1, WTq1, 1024, 1024);
    transpose_cvt<<<dim3(32, 32), tb, 0, stream>>>(Wk1, WTk1, 1024, 1024);
    transpose_cvt<<<dim3(32, 32), tb, 0, stream>>>(Wv1, WTv1, 1024, 1024);
    transpose_cvt<<<dim3(32, 32), tb, 0, stream>>>(Wo1, WTo1, 1024, 1024);
    transpose_cvt<<<dim3(32, 32), tb, 0, stream>>>(Wq2, WTq2, 1024, 1024);
    transpose_cvt<<<dim3(32, 32), tb, 0, stream>>>(Wk2, WTk2, 1024, 1024);
    transpose_cvt<<<dim3(32, 32), tb, 0, stream>>>(Wv2, WTv2, 1024, 1024);
    transpose_cvt<<<dim3(32, 32), tb, 0, stream>>>(Wo2, WTo2, 1024, 1024);
    transpose_cvt<<<dim3(128, 32), tb, 0, stream>>>(Wf1, WTF1, 1024, 4096);
    transpose_cvt<<<dim3(32, 128), tb, 0, stream>>>(Wf2, WTF2, 4096, 1024);

    // ---------------- self-attention ----------------
    gemm_bt<128, 128, false, false, false><<<dim3(8, 32, 1), 256, 0, stream>>>(
        Xbf, WTq1, bq1, Qb, 1024, 1024, 1024, 1024, 0, 0, 0, 0, 0, 0, 1, nullptr, 0.f);
    gemm_bt<128, 128, false, false, false><<<dim3(8, 32, 1), 256, 0, stream>>>(
        Xbf, WTk1, bk1, Kb, 1024, 1024, 1024, 1024, 0, 0, 0, 0, 0, 0, 1, nullptr, 0.f);
    gemm_bt<128, 128, false, false, false><<<dim3(8, 32, 1), 256, 0, stream>>>(
        Xbf, WTv1, bv1, Vb, 1024, 1024, 1024, 1024, 0, 0, 0, 0, 0, 0, 1, nullptr, 0.f);
    transpose_v<<<dim3(32, 2, 64), tb, 0, stream>>>(Vb, VT);
    // logits(fp32) = Q @ K^T / 8 + mask  -> AW1
    gemm_bt<128, 128, false, true, false><<<dim3(8, 8, 64), 256, 0, stream>>>(
        Qb, Kb, nullptr, AW1, 1024, 1024, 1024, 64,
        1048576, 64, 1048576, 64, 16777216, 1048576, 16, MSUB, 0.125f);
    softmax_rows_f32<<<65536, 256, 0, stream>>>(AW1);
    // attn = P(fp32) @ V  -> ATT (B,S,D) bf16
    gemm_bt<128, 64, false, false, true><<<dim3(1, 8, 64), 256, 0, stream>>>(
        AW1, VT, nullptr, ATT, 1024, 1024, 1024, 1024,
        16777216, 1048576, 1048576, 65536, 1048576, 64, 16, nullptr, 0.f);
    gemm_bt<128, 128, false, false, false><<<dim3(8, 32, 1), 256, 0, stream>>>(
        ATT, WTo1, bo1, TMP, 1024, 1024, 1024, 1024, 0, 0, 0, 0, 0, 0, 1, nullptr, 0.f);
    add_ln<true><<<4096, 256, 0, stream>>>(TMP, X, g1, be1, O1, nullptr);

    // ---------------- cross-attention ----------------
    gemm_bt<128, 128, false, false, false><<<dim3(8, 32, 1), 256, 0, stream>>>(
        O1, WTq2, bq2, Qb, 1024, 1024, 1024, 1024, 0, 0, 0, 0, 0, 0, 1, nullptr, 0.f);
    gemm_bt<128, 128, false, false, false><<<dim3(8, 32, 1), 256, 0, stream>>>(
        ENCb, WTk2, bk2, Kb, 1024, 1024, 1024, 1024, 0, 0, 0, 0, 0, 0, 1, nullptr, 0.f);
    gemm_bt<128, 128, false, false, false><<<dim3(8, 32, 1), 256, 0, stream>>>(
        ENCb, WTv2, bv2, Vb, 1024, 1024, 1024, 1024, 0, 0, 0, 0, 0, 0, 1, nullptr, 0.f);
    transpose_v<<<dim3(32, 2, 64), tb, 0, stream>>>(Vb, VT);
    gemm_bt<128, 128, false, true, false><<<dim3(8, 8, 64), 256, 0, stream>>>(
        Qb, Kb, nullptr, AW2, 1024, 1024, 1024, 64,
        1048576, 64, 1048576, 64, 16777216, 1048576, 16, MPAD, 0.125f);
    softmax_rows_f32<<<65536, 256, 0, stream>>>(AW2);
    gemm_bt<128, 64, false, false, true><<<dim3(1, 8, 64), 256, 0, stream>>>(
        AW2, VT, nullptr, ATT, 1024, 1024, 1024, 1024,
        16777216, 1048576, 1048576, 65536, 1048576, 64, 16, nullptr, 0.f);
    gemm_bt<128, 128, false, false, false><<<dim3(8, 32, 1), 256, 0, stream>>>(
        ATT, WTo2, bo2, TMP, 1024, 1024, 1024, 1024, 0, 0, 0, 0, 0, 0, 1, nullptr, 0.f);
    add_ln<false><<<4096, 256, 0, stream>>>(TMP, O1, g2, be2, O2, nullptr);

    // ---------------- FFN ----------------
    gemm_bt<128, 128, true, false, false><<<dim3(32, 32, 1), 256, 0, stream>>>(
        O2, WTF1, bf1, Hb, 1024, 1024, 4096, 1024, 0, 0, 0, 0, 0, 0, 1, nullptr, 0.f);
    gemm_bt<128, 128, false, false, false><<<dim3(8, 32, 1), 256, 0, stream>>>(
        Hb, WTF2, bf2v, TMP, 4096, 4096, 1024, 4096, 0, 0, 0, 0, 0, 0, 1, nullptr, 0.f);
    add_ln<false><<<4096, 256, 0, stream>>>(TMP, O2, g3, be3, nullptr, OUT3);
}